// Round 13
// baseline (55.962 us; speedup 1.0000x reference)
//
#include <hip/hip_runtime.h>
#include <hip/hip_bf16.h>

// TripletLoss: B=4096, D=1024.
// out[0] = loss scalar, out[1..] = distances (4096x4096 f32, row-major).
// Path: per-row-scaled int8 GEMM (exact i32 accumulate), d = 1 - sA*sB*acc.
// ws: qT [B*D] i8, qG [B*D] i8, sT [B] f32, sG [B] f32, hn_key [B] i32, pos [B] f32.

typedef int i32x4 __attribute__((ext_vector_type(4)));

__device__ __forceinline__ void gload16(const void* g, void* l) {
  __builtin_amdgcn_global_load_lds(
      (__attribute__((address_space(1))) void*)(g),
      (__attribute__((address_space(3))) void*)(l), 16, 0, 0);
}

// order-preserving float->int key
__device__ __forceinline__ int fkey(float x) {
  int u = __float_as_int(x);
  return u >= 0 ? u : (u ^ 0x7fffffff);
}
__device__ __forceinline__ float funkey(int k) {
  return __int_as_float(k >= 0 ? k : (k ^ 0x7fffffff));
}

// ---------------------------------------------------------------- quantize
__global__ __launch_bounds__(256) void k_quant(
    const float* __restrict__ t, const float* __restrict__ g,
    char4* __restrict__ qt, char4* __restrict__ qg,
    float* __restrict__ st, float* __restrict__ sg,
    int* __restrict__ hn_key, int D) {
  const int row = blockIdx.x;
  const float* src = (blockIdx.y ? g : t) + (size_t)row * D;
  char4*      dst  = (blockIdx.y ? qg : qt) + (size_t)row * (D >> 2);
  float*      sout = blockIdx.y ? sg : st;

  float4 v = ((const float4*)src)[threadIdx.x];
  float ss = v.x * v.x + v.y * v.y + v.z * v.z + v.w * v.w;
  float am = fmaxf(fmaxf(fabsf(v.x), fabsf(v.y)), fmaxf(fabsf(v.z), fabsf(v.w)));
#pragma unroll
  for (int off = 32; off; off >>= 1) {
    ss += __shfl_down(ss, off);
    am = fmaxf(am, __shfl_down(am, off));
  }
  __shared__ float rs[4], rm[4];
  if ((threadIdx.x & 63) == 0) { rs[threadIdx.x >> 6] = ss; rm[threadIdx.x >> 6] = am; }
  __syncthreads();
  const float ssT = rs[0] + rs[1] + rs[2] + rs[3];
  const float amT = fmaxf(fmaxf(rm[0], rm[1]), fmaxf(rm[2], rm[3]));
  const float qs  = 127.0f / fmaxf(amT, 1e-20f);

  char4 o;
  o.x = (char)__float2int_rn(v.x * qs);
  o.y = (char)__float2int_rn(v.y * qs);
  o.z = (char)__float2int_rn(v.z * qs);
  o.w = (char)__float2int_rn(v.w * qs);
  dst[threadIdx.x] = o;

  if (threadIdx.x == 0) {
    sout[row] = fmaxf(amT, 1e-20f) / (127.0f * fmaxf(sqrtf(ssT), 1e-12f));
    if (blockIdx.y == 0) hn_key[row] = __float_as_int(1e9f);
  }
}

// ---------------------------------------------------------------- GEMM fused
// 256x256 output per block, M-SPLIT TWO-PASS: pass p computes rows p*128..+127
// over all K (A tile 128x128B, B tile 256x128B, BK=128 i8), then immediately
// stores that half (fused hard-neg-min epilogue). Pass 0's 32MB device-wide
// store burst drains under pass 1's compute -> exposed store tail halves.
// Unified vt=0..15 loop, dbuf alternates continuously; stage vt+1 at tile
// top (6 issues: 2 A + 4 B), ONE {vmcnt(0); s_barrier} boundary per vt.
// mfma_i32_16x16x64_i8; 8 waves (2M x 4N), per-wave 64x64 per pass.
// LDS swizzle: (r,kb) at byte r*128 + (kb ^ ((r&7)<<4)); ks=1 read offset is
// (64+khi)^sw (XOR — bits 4-6 overlap the swizzle). No setprio (m190).
__global__ __launch_bounds__(512, 2) void k_gemm_fused(
    const char* __restrict__ A, const char* __restrict__ Bm,
    const float* __restrict__ sA, const float* __restrict__ sB,
    const int* __restrict__ labels, float* __restrict__ Dout,
    int* __restrict__ hn_key, float* __restrict__ pos, int N, int K) {
  __shared__ __align__(16) char Abuf[2][128 * 128];
  __shared__ __align__(16) char Bbuf[2][256 * 128];
  __shared__ int   labR[256], labC[256], hnmin[256];
  __shared__ float sAr[256], sBc[256];

  const int tid  = threadIdx.x;
  const int lane = tid & 63;
  const int w    = tid >> 6;
  const int waveM = w >> 2, waveN = w & 3;   // 2M x 4N, per-wave 64x64/pass

  // T1: XCD-aware bijective swizzle (256 blocks, 32 per XCD)
  const int nb  = N >> 8;               // 16
  const int cpx = (nb * nb) >> 3;       // 32
  const int bid = blockIdx.x;
  const int swz = (bid & 7) * cpx + (bid >> 3);
  const int rowBase = (swz / nb) * 256;
  const int colBase = (swz % nb) * 256;

  // staging: 16B/thread/issue; issue covers 64 rows (rr) x 128B cols.
  const int rr   = tid >> 3;                       // 0..63
  const int scol = ((tid & 7) ^ (rr & 7)) << 4;    // inverse-swizzled src bytes
  const int ldsOff = tid * 16;                     // bytes within a 64-row sub

  // fragment read offsets (bytes, rows stride 128B)
  const int sw  = (lane & 7) << 4;
  const int khi = (lane >> 4) << 4;
  const int kx0 = khi ^ sw;                        // ks=0 (k 0..63)
  const int kx1 = (64 + khi) ^ sw;                 // ks=1 (k 64..127) — XOR!
  const int aBase = (waveM * 64 + (lane & 15)) * 128;
  const int bBase = (waveN * 64 + (lane & 15)) * 128;

  // ---- prologue: stage vt=0 (pass0 A rows 0-127, B, kt=0); arrays init
  {
    const char* aSp = A + (size_t)(rowBase + rr) * K + scol;
    const char* bSp = Bm + (size_t)(colBase + rr) * K + scol;
    gload16(aSp,                    &Abuf[0][ldsOff]);
    gload16(aSp + (size_t)64 * K,   &Abuf[0][8192 + ldsOff]);
#pragma unroll
    for (int j = 0; j < 4; ++j)
      gload16(bSp + (size_t)(j * 64) * K, &Bbuf[0][j * 8192 + ldsOff]);
  }
  if (tid < 256) {
    labR[tid]  = labels[rowBase + tid];
    sAr[tid]   = sA[rowBase + tid];
    hnmin[tid] = __float_as_int(1e9f);
  } else {
    labC[tid - 256] = labels[colBase + (tid - 256)];
    sBc[tid - 256]  = sB[colBase + (tid - 256)];
  }
  asm volatile("s_waitcnt vmcnt(0) lgkmcnt(0)" ::: "memory");
  __builtin_amdgcn_s_barrier();
  asm volatile("" ::: "memory");

  const int ci = lane & 15;
  const int r4 = (lane >> 4) << 2;
  const bool diagBlk = (rowBase == colBase);

#pragma unroll 1
  for (int p = 0; p < 2; ++p) {
    i32x4 acc[4][4];
#pragma unroll
    for (int m = 0; m < 4; ++m)
#pragma unroll
      for (int n = 0; n < 4; ++n) acc[m][n] = (i32x4){0, 0, 0, 0};

#pragma unroll 1
    for (int t = 0; t < 8; ++t) {
      const int vt = p * 8 + t;
      const int c = vt & 1;
      const int nvt = vt + 1;

      // ---- stage vt+1 at tile top (max cover before boundary)
      if (nvt < 16) {
        const int pn = nvt >> 3, ktn = nvt & 7;
        char* An = &Abuf[c ^ 1][0];
        char* Bn = &Bbuf[c ^ 1][0];
        const char* aSp = A + (size_t)(rowBase + pn * 128 + rr) * K
                            + (size_t)ktn * 128 + scol;
        const char* bSp = Bm + (size_t)(colBase + rr) * K
                             + (size_t)ktn * 128 + scol;
        gload16(aSp,                  An + ldsOff);
        gload16(aSp + (size_t)64 * K, An + 8192 + ldsOff);
#pragma unroll
        for (int j = 0; j < 4; ++j)
          gload16(bSp + (size_t)(j * 64) * K, Bn + j * 8192 + ldsOff);
      }

      const char* Ab = &Abuf[c][0];
      const char* Bb = &Bbuf[c][0];
      i32x4 af[4][2], bf[4][2];
#pragma unroll
      for (int m = 0; m < 4; ++m) {
        af[m][0] = *(const i32x4*)(Ab + aBase + m * 2048 + kx0);
        af[m][1] = *(const i32x4*)(Ab + aBase + m * 2048 + kx1);
      }
#pragma unroll
      for (int n = 0; n < 4; ++n) {
        bf[n][0] = *(const i32x4*)(Bb + bBase + n * 2048 + kx0);
        bf[n][1] = *(const i32x4*)(Bb + bBase + n * 2048 + kx1);
      }
#pragma unroll
      for (int ks = 0; ks < 2; ++ks)
#pragma unroll
        for (int m = 0; m < 4; ++m)
#pragma unroll
          for (int n = 0; n < 4; ++n)
            acc[m][n] = __builtin_amdgcn_mfma_i32_16x16x64_i8(
                af[m][ks], bf[n][ks], acc[m][n], 0, 0, 0);

      // ---- boundary (one sync per vt): own vt+1 loads landed (full-tile
      //      cover -> near-free) + all waves done reading buf c.
      if (nvt < 16) {
        asm volatile("s_waitcnt vmcnt(0)" ::: "memory");
        __builtin_amdgcn_s_barrier();
        asm volatile("" ::: "memory");
      }
    }

    // ---- pass-p epilogue: store rows p*128..+127 NOW (pass0's stores
    //      drain under pass1's compute); fused hard-neg min + diag pos.
#pragma unroll
    for (int m = 0; m < 4; ++m) {
      const int gilB = p * 128 + waveM * 64 + m * 16 + r4;
#pragma unroll
      for (int r = 0; r < 4; ++r) {
        const int gil = gilB + r;
        const int li  = labR[gil];
        const float sa = sAr[gil];
        const size_t gi = (size_t)(rowBase + gil);
        float mn = 1e9f;
#pragma unroll
        for (int n = 0; n < 4; ++n) {
          const int gjl = waveN * 64 + n * 16 + ci;
          const float d = 1.0f - sa * sBc[gjl] * (float)acc[m][n][r];
          Dout[gi * N + (colBase + gjl)] = d;
          if (labC[gjl] != li) mn = fminf(mn, d);
          if (diagBlk && gil == gjl) pos[gi] = d;
        }
#pragma unroll
        for (int off = 1; off < 16; off <<= 1) mn = fminf(mn, __shfl_xor(mn, off));
        if (ci == 0) atomicMin(&hnmin[gil], fkey(mn));
      }
    }
  }

  __syncthreads();
  if (tid < 256) atomicMin(&hn_key[rowBase + tid], hnmin[tid]);
}

// ---------------------------------------------------------------- final sum
__global__ __launch_bounds__(256) void k_final(
    const int* __restrict__ hn_key, const float* __restrict__ pos,
    float* __restrict__ out, int N) {
  float s = 0.f;
  for (int i = threadIdx.x; i < N; i += 256) {
    const float hn = funkey(hn_key[i]);
    const float pr = pos[i] - hn + 1.0f;   // MARGIN = 1.0
    s += pr > 0.f ? pr : 0.f;              // hn==1e9 rows (no negatives) -> 0
  }
#pragma unroll
  for (int off = 32; off; off >>= 1) s += __shfl_down(s, off);
  __shared__ float red[4];
  if ((threadIdx.x & 63) == 0) red[threadIdx.x >> 6] = s;
  __syncthreads();
  if (threadIdx.x == 0) out[0] = (red[0] + red[1] + red[2] + red[3]) / (float)N;
}

extern "C" void kernel_launch(void* const* d_in, const int* in_sizes, int n_in,
                              void* d_out, int out_size, void* d_ws, size_t ws_size,
                              hipStream_t stream) {
  const float* t      = (const float*)d_in[0];
  const float* g      = (const float*)d_in[1];
  const int*   labels = (const int*)d_in[2];
  const int Bn = in_sizes[2];          // 4096
  const int D  = in_sizes[0] / Bn;     // 1024

  float* out  = (float*)d_out;
  float* dist = out + 1;

  char*  qT     = (char*)d_ws;
  char*  qG     = qT + (size_t)Bn * D;
  float* sT     = (float*)(qG + (size_t)Bn * D);
  float* sG     = sT + Bn;
  int*   hn_key = (int*)(sG + Bn);
  float* pos    = (float*)(hn_key + Bn);

  k_quant<<<dim3(Bn, 2), 256, 0, stream>>>(t, g, (char4*)qT, (char4*)qG,
                                           sT, sG, hn_key, D);
  const int nb = Bn / 256;
  k_gemm_fused<<<dim3(nb * nb), 512, 0, stream>>>(qT, qG, sT, sG, labels, dist,
                                                  hn_key, pos, Bn, D);
  k_final<<<1, 256, 0, stream>>>(hn_key, pos, out, Bn);
}

// Round 14
// 48.686 us; speedup vs baseline: 1.1495x; 1.1495x over previous
//
#include <hip/hip_runtime.h>
#include <hip/hip_bf16.h>

// TripletLoss: B=4096, D=1024.
// out[0] = loss scalar, out[1..] = distances (4096x4096 f32, row-major).
// Path: per-row-scaled int8 GEMM (exact i32 accumulate), d = 1 - sA*sB*acc.
// ws: qT [B*D] i8, qG [B*D] i8, sT [B] f32, sG [B] f32, hn_key [B] i32, pos [B] f32.
// R14 = R11 (best measured, 49.9us) minus s_setprio (m190: negative on
// lockstep GEMM). No other changes.

typedef int i32x4 __attribute__((ext_vector_type(4)));

__device__ __forceinline__ void gload16(const void* g, void* l) {
  __builtin_amdgcn_global_load_lds(
      (__attribute__((address_space(1))) void*)(g),
      (__attribute__((address_space(3))) void*)(l), 16, 0, 0);
}

// order-preserving float->int key
__device__ __forceinline__ int fkey(float x) {
  int u = __float_as_int(x);
  return u >= 0 ? u : (u ^ 0x7fffffff);
}
__device__ __forceinline__ float funkey(int k) {
  return __int_as_float(k >= 0 ? k : (k ^ 0x7fffffff));
}

// ---------------------------------------------------------------- quantize
__global__ __launch_bounds__(256) void k_quant(
    const float* __restrict__ t, const float* __restrict__ g,
    char4* __restrict__ qt, char4* __restrict__ qg,
    float* __restrict__ st, float* __restrict__ sg,
    int* __restrict__ hn_key, int D) {
  const int row = blockIdx.x;
  const float* src = (blockIdx.y ? g : t) + (size_t)row * D;
  char4*      dst  = (blockIdx.y ? qg : qt) + (size_t)row * (D >> 2);
  float*      sout = blockIdx.y ? sg : st;

  float4 v = ((const float4*)src)[threadIdx.x];
  float ss = v.x * v.x + v.y * v.y + v.z * v.z + v.w * v.w;
  float am = fmaxf(fmaxf(fabsf(v.x), fabsf(v.y)), fmaxf(fabsf(v.z), fabsf(v.w)));
#pragma unroll
  for (int off = 32; off; off >>= 1) {
    ss += __shfl_down(ss, off);
    am = fmaxf(am, __shfl_down(am, off));
  }
  __shared__ float rs[4], rm[4];
  if ((threadIdx.x & 63) == 0) { rs[threadIdx.x >> 6] = ss; rm[threadIdx.x >> 6] = am; }
  __syncthreads();
  const float ssT = rs[0] + rs[1] + rs[2] + rs[3];
  const float amT = fmaxf(fmaxf(rm[0], rm[1]), fmaxf(rm[2], rm[3]));
  const float qs  = 127.0f / fmaxf(amT, 1e-20f);

  char4 o;
  o.x = (char)__float2int_rn(v.x * qs);
  o.y = (char)__float2int_rn(v.y * qs);
  o.z = (char)__float2int_rn(v.z * qs);
  o.w = (char)__float2int_rn(v.w * qs);
  dst[threadIdx.x] = o;

  if (threadIdx.x == 0) {
    sout[row] = fmaxf(amT, 1e-20f) / (127.0f * fmaxf(sqrtf(ssT), 1e-12f));
    if (blockIdx.y == 0) hn_key[row] = __float_as_int(1e9f);
  }
}

// ---------------------------------------------------------------- GEMM fused
// 256x256 tile, BK=128 (i8), 512 thr = 8 waves (2M x 4N), per-wave 128x64.
// Counted-vmcnt 4-phase schedule: per K-tile, 4 quadrant phases
// {ds_read frags | 2 gload_lds stage -> s_barrier -> MFMA -> s_barrier};
// tile t+1's 8 loads spread across tile t's phases; tile t+2's A-half0
// tail-issues into the freed buffer BEFORE the boundary wait, so the
// steady-state boundary is vmcnt(2), never 0.
// LDS swizzle: data (r,kb) at byte r*128 + (kb ^ ((r&7)<<4)) — XOR spans
// bits 4-6, so the ks=1 read offset is (64+khi)^sw, NOT (khi^sw)+64.
__global__ __launch_bounds__(512, 2) void k_gemm_fused(
    const char* __restrict__ A, const char* __restrict__ Bm,
    const float* __restrict__ sA, const float* __restrict__ sB,
    const int* __restrict__ labels, float* __restrict__ Dout,
    int* __restrict__ hn_key, float* __restrict__ pos, int N, int K) {
  __shared__ __align__(16) char Abuf[2][256 * 128];
  __shared__ __align__(16) char Bbuf[2][256 * 128];
  __shared__ int   labR[256], labC[256], hnmin[256];
  __shared__ float sAr[256], sBc[256];

  const int tid  = threadIdx.x;
  const int lane = tid & 63;
  const int w    = tid >> 6;
  const int waveM = w >> 2, waveN = w & 3;   // 2M x 4N, per-wave 128x64

  // T1: XCD-aware bijective swizzle (256 blocks, 32 per XCD)
  const int nb  = N >> 8;               // 16
  const int cpx = (nb * nb) >> 3;       // 32
  const int bid = blockIdx.x;
  const int swz = (bid & 7) * cpx + (bid >> 3);
  const int rowBase = (swz / nb) * 256;
  const int colBase = (swz % nb) * 256;

  // staging: sub j covers rows j*64 + tid/8; 16B/thread/issue.
  const int rr   = tid >> 3;                       // 0..63
  const int scol = ((tid & 7) ^ (rr & 7)) << 4;    // inverse-swizzled src bytes
  const char* aS = A  + (size_t)(rowBase + rr) * K + scol;
  const char* bS = Bm + (size_t)(colBase + rr) * K + scol;
  const int ldsOff = tid * 16;                     // bytes within a 64-row sub

  // fragment read offsets (bytes, rows stride 128B)
  const int sw  = (lane & 7) << 4;
  const int khi = (lane >> 4) << 4;
  const int kx0 = khi ^ sw;                        // ks=0 (k 0..63)
  const int kx1 = (64 + khi) ^ sw;                 // ks=1 (k 64..127) — XOR!
  const int aBase = (waveM * 128 + (lane & 15)) * 128;
  const int bBase = (waveN * 64  + (lane & 15)) * 128;

  const int NT = K >> 7;   // 8

  // ---- prologue: tile0 full (8 issues) + tile1 A-half0 (2); arrays init
#pragma unroll
  for (int h = 0; h < 2; ++h)
#pragma unroll
    for (int j = 0; j < 2; ++j) {
      gload16(aS + (size_t)(h * 128 + j * 64) * K,
              &Abuf[0][h * 16384 + j * 8192 + ldsOff]);
      gload16(bS + (size_t)(h * 128 + j * 64) * K,
              &Bbuf[0][h * 16384 + j * 8192 + ldsOff]);
    }
  if (NT > 1) {
    gload16(aS + (size_t)128,                    &Abuf[1][0 * 8192 + ldsOff]);
    gload16(aS + (size_t)64 * K + 128,           &Abuf[1][1 * 8192 + ldsOff]);
  }
  if (tid < 256) {
    labR[tid]  = labels[rowBase + tid];
    sAr[tid]   = sA[rowBase + tid];
    hnmin[tid] = __float_as_int(1e9f);
  } else {
    labC[tid - 256] = labels[colBase + (tid - 256)];
    sBc[tid - 256]  = sB[colBase + (tid - 256)];
  }
  if (NT > 1) asm volatile("s_waitcnt vmcnt(2) lgkmcnt(0)" ::: "memory");
  else        asm volatile("s_waitcnt vmcnt(0) lgkmcnt(0)" ::: "memory");
  __builtin_amdgcn_s_barrier();
  asm volatile("" ::: "memory");

  i32x4 acc[8][4];
#pragma unroll
  for (int m = 0; m < 8; ++m)
#pragma unroll
    for (int n = 0; n < 4; ++n) acc[m][n] = (i32x4){0, 0, 0, 0};

  for (int t = 0; t < NT; ++t) {
    const int c = t & 1;
    const char* Ab = &Abuf[c][0];
    const char* Bb = &Bbuf[c][0];
    char* An = &Abuf[c ^ 1][0];
    char* Bn = &Bbuf[c ^ 1][0];
    const bool nx = (t + 1 < NT);
    const size_t ko1 = (size_t)(t + 1) * 128;

    i32x4 af[4][2], bf0[2][2], bf1[2][2];

    // ---- P0: read af(m-lo)+bf0(n-lo); stage t+1 A-half1; MFMA Q(0,0)
#pragma unroll
    for (int m = 0; m < 4; ++m) {
      af[m][0] = *(const i32x4*)(Ab + aBase + m * 2048 + kx0);
      af[m][1] = *(const i32x4*)(Ab + aBase + m * 2048 + kx1);
    }
#pragma unroll
    for (int n = 0; n < 2; ++n) {
      bf0[n][0] = *(const i32x4*)(Bb + bBase + n * 2048 + kx0);
      bf0[n][1] = *(const i32x4*)(Bb + bBase + n * 2048 + kx1);
    }
    if (nx) {
      gload16(aS + (size_t)128 * K + ko1,        An + 16384 + ldsOff);
      gload16(aS + (size_t)192 * K + ko1,        An + 16384 + 8192 + ldsOff);
    }
    __builtin_amdgcn_s_barrier();
#pragma unroll
    for (int ks = 0; ks < 2; ++ks)
#pragma unroll
      for (int m = 0; m < 4; ++m)
#pragma unroll
        for (int n = 0; n < 2; ++n)
          acc[m][n] = __builtin_amdgcn_mfma_i32_16x16x64_i8(
              af[m][ks], bf0[n][ks], acc[m][n], 0, 0, 0);
    __builtin_amdgcn_s_barrier();

    // ---- P1: read bf1(n-hi); stage t+1 B-half0; MFMA Q(0,1)
#pragma unroll
    for (int n = 0; n < 2; ++n) {
      bf1[n][0] = *(const i32x4*)(Bb + bBase + 4096 + n * 2048 + kx0);
      bf1[n][1] = *(const i32x4*)(Bb + bBase + 4096 + n * 2048 + kx1);
    }
    if (nx) {
      gload16(bS + ko1,                          Bn + ldsOff);
      gload16(bS + (size_t)64 * K + ko1,         Bn + 8192 + ldsOff);
    }
    __builtin_amdgcn_s_barrier();
#pragma unroll
    for (int ks = 0; ks < 2; ++ks)
#pragma unroll
      for (int m = 0; m < 4; ++m)
#pragma unroll
        for (int n = 0; n < 2; ++n)
          acc[m][2 + n] = __builtin_amdgcn_mfma_i32_16x16x64_i8(
              af[m][ks], bf1[n][ks], acc[m][2 + n], 0, 0, 0);
    __builtin_amdgcn_s_barrier();

    // ---- P2: read af(m-hi); stage t+1 B-half1; MFMA Q(1,1)
#pragma unroll
    for (int m = 0; m < 4; ++m) {
      af[m][0] = *(const i32x4*)(Ab + aBase + 8192 + m * 2048 + kx0);
      af[m][1] = *(const i32x4*)(Ab + aBase + 8192 + m * 2048 + kx1);
    }
    if (nx) {
      gload16(bS + (size_t)128 * K + ko1,        Bn + 16384 + ldsOff);
      gload16(bS + (size_t)192 * K + ko1,        Bn + 16384 + 8192 + ldsOff);
    }
    __builtin_amdgcn_s_barrier();
#pragma unroll
    for (int ks = 0; ks < 2; ++ks)
#pragma unroll
      for (int m = 0; m < 4; ++m)
#pragma unroll
        for (int n = 0; n < 2; ++n)
          acc[4 + m][2 + n] = __builtin_amdgcn_mfma_i32_16x16x64_i8(
              af[m][ks], bf1[n][ks], acc[4 + m][2 + n], 0, 0, 0);
    __builtin_amdgcn_s_barrier();

    // ---- P3: MFMA Q(1,0) (af m-hi + bf0 still live); no reads, no stage
#pragma unroll
    for (int ks = 0; ks < 2; ++ks)
#pragma unroll
      for (int m = 0; m < 4; ++m)
#pragma unroll
        for (int n = 0; n < 2; ++n)
          acc[4 + m][n] = __builtin_amdgcn_mfma_i32_16x16x64_i8(
              af[m][ks], bf0[n][ks], acc[4 + m][n], 0, 0, 0);
    __builtin_amdgcn_s_barrier();          // all reads of buf c complete
    asm volatile("" ::: "memory");

    // ---- boundary: tail-issue t+2 A-half0 into freed buf c, counted wait
    if (nx) {
      if (t + 2 < NT) {
        const size_t ko2 = (size_t)(t + 2) * 128;
        gload16(aS + ko2,                  &Abuf[c][0] + ldsOff);
        gload16(aS + (size_t)64 * K + ko2, &Abuf[c][0] + 8192 + ldsOff);
        asm volatile("s_waitcnt vmcnt(2)" ::: "memory");   // t+1 landed
      } else {
        asm volatile("s_waitcnt vmcnt(0)" ::: "memory");
      }
      __builtin_amdgcn_s_barrier();        // all waves' t+1 loads landed
      asm volatile("" ::: "memory");
    }
  }

  // ---------------- fused epilogue: store distances + per-row hard-neg min
  const int ci = lane & 15;
  const int r4 = (lane >> 4) << 2;
  const bool diagBlk = (rowBase == colBase);
#pragma unroll
  for (int m = 0; m < 8; ++m) {
    const int gilB = waveM * 128 + m * 16 + r4;
#pragma unroll
    for (int r = 0; r < 4; ++r) {
      const int gil = gilB + r;
      const int li  = labR[gil];
      const float sa = sAr[gil];
      const size_t gi = (size_t)(rowBase + gil);
      float mn = 1e9f;
#pragma unroll
      for (int n = 0; n < 4; ++n) {
        const int gjl = waveN * 64 + n * 16 + ci;
        const float d = 1.0f - sa * sBc[gjl] * (float)acc[m][n][r];
        Dout[gi * N + (colBase + gjl)] = d;
        if (labC[gjl] != li) mn = fminf(mn, d);
        if (diagBlk && gil == gjl) pos[gi] = d;
      }
#pragma unroll
      for (int off = 1; off < 16; off <<= 1) mn = fminf(mn, __shfl_xor(mn, off));
      if (ci == 0) atomicMin(&hnmin[gil], fkey(mn));
    }
  }
  __syncthreads();
  if (tid < 256) atomicMin(&hn_key[rowBase + tid], hnmin[tid]);
}

// ---------------------------------------------------------------- final sum
__global__ __launch_bounds__(256) void k_final(
    const int* __restrict__ hn_key, const float* __restrict__ pos,
    float* __restrict__ out, int N) {
  float s = 0.f;
  for (int i = threadIdx.x; i < N; i += 256) {
    const float hn = funkey(hn_key[i]);
    const float pr = pos[i] - hn + 1.0f;   // MARGIN = 1.0
    s += pr > 0.f ? pr : 0.f;              // hn==1e9 rows (no negatives) -> 0
  }
#pragma unroll
  for (int off = 32; off; off >>= 1) s += __shfl_down(s, off);
  __shared__ float red[4];
  if ((threadIdx.x & 63) == 0) red[threadIdx.x >> 6] = s;
  __syncthreads();
  if (threadIdx.x == 0) out[0] = (red[0] + red[1] + red[2] + red[3]) / (float)N;
}

extern "C" void kernel_launch(void* const* d_in, const int* in_sizes, int n_in,
                              void* d_out, int out_size, void* d_ws, size_t ws_size,
                              hipStream_t stream) {
  const float* t      = (const float*)d_in[0];
  const float* g      = (const float*)d_in[1];
  const int*   labels = (const int*)d_in[2];
  const int Bn = in_sizes[2];          // 4096
  const int D  = in_sizes[0] / Bn;     // 1024

  float* out  = (float*)d_out;
  float* dist = out + 1;

  char*  qT     = (char*)d_ws;
  char*  qG     = qT + (size_t)Bn * D;
  float* sT     = (float*)(qG + (size_t)Bn * D);
  float* sG     = sT + Bn;
  int*   hn_key = (int*)(sG + Bn);
  float* pos    = (float*)(hn_key + Bn);

  k_quant<<<dim3(Bn, 2), 256, 0, stream>>>(t, g, (char4*)qT, (char4*)qG,
                                           sT, sG, hn_key, D);
  const int nb = Bn / 256;
  k_gemm_fused<<<dim3(nb * nb), 512, 0, stream>>>(qT, qG, sT, sG, labels, dist,
                                                  hn_key, pos, Bn, D);
  k_final<<<1, 256, 0, stream>>>(hn_key, pos, out, Bn);
}